// Round 17
// baseline (401.203 us; speedup 1.0000x reference)
//
#include <hip/hip_runtime.h>
#include <stdint.h>

// Problem constants
#define TB 4
#define TT 8192
#define TD 1024
#define TS 32
#define TL 256
#define BT 32768   // TB*TT

typedef unsigned short u16;
typedef __bf16 bf16x8 __attribute__((ext_vector_type(8)));
typedef float f32x4 __attribute__((ext_vector_type(4)));

typedef uint32_t u32_g __attribute__((address_space(1)));
typedef uint32_t u32_l __attribute__((address_space(3)));

#define VMWAIT(N) asm volatile("s_waitcnt vmcnt(" #N ")" ::: "memory")
#define LGKM0()   asm volatile("s_waitcnt lgkmcnt(0)" ::: "memory")

__device__ __forceinline__ u16 f2b(float f){
  union { float f; uint32_t u; } a; a.f = f;
  uint32_t r = a.u + 0x7FFFu + ((a.u >> 16) & 1u);
  return (u16)(r >> 16);
}
__device__ __forceinline__ float b2f(u16 u){
  union { uint32_t u; float f; } a; a.u = ((uint32_t)u) << 16;
  return a.f;
}
__device__ __forceinline__ void gll16(const void* g, void* l){
  __builtin_amdgcn_global_load_lds((const u32_g*)g, (u32_l*)l, 16, 0, 0);
}
__device__ __forceinline__ bf16x8 cvt8(const float* p){
  float4 a = *(const float4*)p, b = *(const float4*)(p+4);
  union { u16 s[8]; bf16x8 v; } u;
  u.s[0]=f2b(a.x); u.s[1]=f2b(a.y); u.s[2]=f2b(a.z); u.s[3]=f2b(a.w);
  u.s[4]=f2b(b.x); u.s[5]=f2b(b.y); u.s[6]=f2b(b.z); u.s[7]=f2b(b.w);
  return u.v;
}

// ---- z=0..3: transpose+convert f32 [1024][1024] -> bf16 T[j][i];
//      z=4 (by==0, 16 blocks): q' = bf16(ms @ Wq^T), f32 inputs inline-cvt ----
__global__ void k_tran(const float* __restrict__ w0, const float* __restrict__ w1,
                       const float* __restrict__ w2, const float* __restrict__ w3,
                       const float* __restrict__ ms, const float* __restrict__ Wq,
                       u16* __restrict__ t0, u16* __restrict__ t1,
                       u16* __restrict__ t2, u16* __restrict__ t3,
                       u16* __restrict__ qb){
  int tid = threadIdx.x, z = blockIdx.z;
  if (z == 4){
    if (blockIdx.y != 0) return;
    int lane = tid & 63, wv = tid >> 6;          // 4 waves
    int r15 = lane & 15, kg = lane >> 4;
    int n0 = blockIdx.x*64 + wv*16;              // 16 blocks x 4 waves x 16 = 1024
    const float* ap = ms + (size_t)r15*TD + kg*8;
    const float* bp = Wq + (size_t)(n0 + r15)*TD + kg*8;
    f32x4 a0 = {0,0,0,0}, a1 = {0,0,0,0};
    #pragma unroll 4
    for (int k0=0; k0<TD; k0+=32){
      bf16x8 b  = cvt8(bp + k0);
      bf16x8 x0 = cvt8(ap + k0);
      bf16x8 x1 = cvt8(ap + 16*TD + k0);
      a0 = __builtin_amdgcn_mfma_f32_16x16x32_bf16(x0, b, a0, 0,0,0);
      a1 = __builtin_amdgcn_mfma_f32_16x16x32_bf16(x1, b, a1, 0,0,0);
    }
    #pragma unroll
    for (int qq=0; qq<4; ++qq){
      qb[(size_t)(kg*4 + qq)*TD + n0 + r15]      = f2b(a0[qq]);
      qb[(size_t)(16 + kg*4 + qq)*TD + n0 + r15] = f2b(a1[qq]);
    }
    return;
  }
  const float* src = (z==0)?w0:(z==1)?w1:(z==2)?w2:w3;
  u16* dst = (z==0)?t0:(z==1)?t1:(z==2)?t2:t3;
  __shared__ float sT[64][65];
  int r0 = blockIdx.y*64, c0 = blockIdx.x*64;
  int lr = tid >> 2, lc = (tid & 3)*16;
  #pragma unroll
  for (int j=0; j<4; ++j){
    float4 v = *(const float4*)(src + (size_t)(r0+lr)*TD + c0 + lc + j*4);
    sT[lr][lc+j*4+0]=v.x; sT[lr][lc+j*4+1]=v.y; sT[lr][lc+j*4+2]=v.z; sT[lr][lc+j*4+3]=v.w;
  }
  __syncthreads();
  int oc = tid >> 2, orh = (tid & 3)*16;
  #pragma unroll
  for (int j=0; j<4; ++j){
    ushort4 u;
    u.x = f2b(sT[orh+j*4+0][oc]);
    u.y = f2b(sT[orh+j*4+1][oc]);
    u.z = f2b(sT[orh+j*4+2][oc]);
    u.w = f2b(sT[orh+j*4+3][oc]);
    *(ushort4*)(dst + (size_t)(c0+oc)*TD + r0 + orh + j*4) = u;
  }
}

// ---- z=0: WgT = (1/32 * WrkT @ WrqT^T)^T  [64 blocks];
//      z=1 (by==0, 8 blocks): qkp = 1/32 * q' @ WkT^T  (f32 [32][1024]) ----
__global__ __launch_bounds__(512) void k_smmw2(
    const u16* __restrict__ WrkT, const u16* __restrict__ WrqT, u16* __restrict__ WgT,
    const u16* __restrict__ qb, const u16* __restrict__ WkT, float* __restrict__ qkp){
  int tid = threadIdx.x, lane = tid & 63, wv = tid >> 6;
  int r15 = lane & 15, kg = lane >> 4;
  if (blockIdx.z == 1){
    if (blockIdx.y != 0) return;
    int n0 = blockIdx.x*128 + wv*16;             // 8 blocks x 8 waves x 16 = 1024
    const u16* ap = qb + (size_t)r15*TD + kg*8;
    const u16* bp = WkT + (size_t)(n0 + r15)*TD + kg*8;
    f32x4 a0 = {0,0,0,0}, a1 = {0,0,0,0};
    #pragma unroll 4
    for (int k0=0; k0<TD; k0+=32){
      bf16x8 b  = *(const bf16x8*)(bp + k0);
      bf16x8 x0 = *(const bf16x8*)(ap + k0);
      bf16x8 x1 = *(const bf16x8*)(ap + 16*TD + k0);
      a0 = __builtin_amdgcn_mfma_f32_16x16x32_bf16(x0, b, a0, 0,0,0);
      a1 = __builtin_amdgcn_mfma_f32_16x16x32_bf16(x1, b, a1, 0,0,0);
    }
    const float sc = 1.0f/32.0f;
    #pragma unroll
    for (int qq=0; qq<4; ++qq){
      qkp[(size_t)(kg*4 + qq)*TD + n0 + r15]      = a0[qq]*sc;
      qkp[(size_t)(16 + kg*4 + qq)*TD + n0 + r15] = a1[qq]*sc;
    }
    return;
  }
  // z==0: WgT
  int wr = wv >> 2, wc = wv & 3;
  int m0 = blockIdx.y*128 + wr*64;
  int n0 = blockIdx.x*128 + wc*32;
  const u16* ap = WrkT + (size_t)(m0 + r15)*TD + kg*8;
  const u16* bp = WrqT + (size_t)(n0 + r15)*TD + kg*8;
  f32x4 acc[4][2];
  #pragma unroll
  for (int i=0;i<4;i++){ f32x4 z={0,0,0,0}; acc[i][0]=z; acc[i][1]=z; }
  #pragma unroll 4
  for (int k0=0; k0<TD; k0+=32){
    bf16x8 b0 = *(const bf16x8*)(bp + k0);
    bf16x8 b1 = *(const bf16x8*)(bp + 16*TD + k0);
    bf16x8 a0 = *(const bf16x8*)(ap + k0);
    bf16x8 a1 = *(const bf16x8*)(ap + 16*TD + k0);
    bf16x8 a2 = *(const bf16x8*)(ap + 32*TD + k0);
    bf16x8 a3 = *(const bf16x8*)(ap + 48*TD + k0);
    acc[0][0] = __builtin_amdgcn_mfma_f32_16x16x32_bf16(a0, b0, acc[0][0], 0,0,0);
    acc[0][1] = __builtin_amdgcn_mfma_f32_16x16x32_bf16(a0, b1, acc[0][1], 0,0,0);
    acc[1][0] = __builtin_amdgcn_mfma_f32_16x16x32_bf16(a1, b0, acc[1][0], 0,0,0);
    acc[1][1] = __builtin_amdgcn_mfma_f32_16x16x32_bf16(a1, b1, acc[1][1], 0,0,0);
    acc[2][0] = __builtin_amdgcn_mfma_f32_16x16x32_bf16(a2, b0, acc[2][0], 0,0,0);
    acc[2][1] = __builtin_amdgcn_mfma_f32_16x16x32_bf16(a2, b1, acc[2][1], 0,0,0);
    acc[3][0] = __builtin_amdgcn_mfma_f32_16x16x32_bf16(a3, b0, acc[3][0], 0,0,0);
    acc[3][1] = __builtin_amdgcn_mfma_f32_16x16x32_bf16(a3, b1, acc[3][1], 0,0,0);
  }
  const float sc = 1.0f/32.0f;
  #pragma unroll
  for (int mf=0; mf<4; ++mf){
    #pragma unroll
    for (int nf=0; nf<2; ++nf){
      int n = n0 + nf*16 + r15;
      #pragma unroll
      for (int qq=0; qq<4; ++qq){
        float v = acc[mf][nf][qq]*sc;
        int m = m0 + mf*16 + kg*4 + qq;
        WgT[(size_t)n*TD + m] = f2b(v);   // transposed store
      }
    }
  }
}

// ---- merged: blocks [0,2048) = conv_dot; blocks [2048,7168) = convert 5 weights -> bf16 ----
__global__ void k_convdot(const float* __restrict__ x, const float* __restrict__ qkp,
                          u16* __restrict__ xb, float* __restrict__ wqk,
                          const float* __restrict__ s0, const float* __restrict__ s1,
                          const float* __restrict__ s2, const float* __restrict__ s3,
                          const float* __restrict__ s4,
                          u16* __restrict__ d0, u16* __restrict__ d1,
                          u16* __restrict__ d2, u16* __restrict__ d3,
                          u16* __restrict__ d4){
  int tid = threadIdx.x;
  if (blockIdx.x >= 2048){
    int i = (blockIdx.x - 2048)*256 + tid;
    int mi = i >> 18, j = i & 262143;
    const float* src; u16* dst;
    if      (mi == 0){ src = s0; dst = d0; }
    else if (mi == 1){ src = s1; dst = d1; }
    else if (mi == 2){ src = s2; dst = d2; }
    else if (mi == 3){ src = s3; dst = d3; }
    else             { src = s4; dst = d4; }
    float4 v = ((const float4*)src)[j];
    ushort4 u; u.x=f2b(v.x); u.y=f2b(v.y); u.z=f2b(v.z); u.w=f2b(v.w);
    ((ushort4*)dst)[j] = u;
    return;
  }
  int lane = tid & 63, wv = tid >> 6;
  long bt0 = (long)blockIdx.x * 16;
  int sseg = (int)((bt0 & (TT-1)) >> 8);
  float qv[16];
  #pragma unroll
  for (int i=0;i<4;i++){
    float4 ta = *(const float4*)(qkp + (size_t)sseg*TD + i*256 + lane*4);
    qv[i*4+0]=ta.x; qv[i*4+1]=ta.y; qv[i*4+2]=ta.z; qv[i*4+3]=ta.w;
  }
  for (int tok = wv; tok < 16; tok += 4){
    long bt = bt0 + tok;
    const float* xr = x + bt*TD;
    float dot = 0.f;
    #pragma unroll
    for (int i=0;i<4;i++){
      float4 t = *(const float4*)(xr + i*256 + lane*4);
      ushort4 u; u.x=f2b(t.x); u.y=f2b(t.y); u.z=f2b(t.z); u.w=f2b(t.w);
      *(ushort4*)(xb + bt*TD + i*256 + lane*4) = u;
      dot += t.x*qv[i*4] + t.y*qv[i*4+1] + t.z*qv[i*4+2] + t.w*qv[i*4+3];
    }
    #pragma unroll
    for (int o=32;o;o>>=1) dot += __shfl_xor(dot, o);
    if (lane == 0) wqk[bt] = dot;
  }
}

// ---- merged: blocks [0,256) = wattn (2 units of 256 thr); [256,384) = smmw (We, WdT) ----
__global__ __launch_bounds__(512) void k_wattn_smm(
    const float* __restrict__ wqk, const u16* __restrict__ xb, u16* __restrict__ xbarb,
    const u16* __restrict__ A1, const u16* __restrict__ W1, u16* __restrict__ O1,  // We (tr0)
    const u16* __restrict__ A2, const u16* __restrict__ W2, u16* __restrict__ O2){ // WdT (tr1)
  __shared__ float sw[2][TL];
  __shared__ float red[2][8];
  __shared__ f32x4 part[2][4][64];
  int tid = threadIdx.x;
  if (blockIdx.x < 256){
    int u = tid >> 8;
    int unit = blockIdx.x*2 + u;
    int bs = unit >> 2, dch = unit & 3;
    int b = bs >> 5, s = bs & 31;
    int t2 = tid & 255, lane = t2 & 63, wv = t2 >> 6;
    long base = (long)b*TT + (long)s*TL;
    float v = wqk[base + t2];
    float m = v;
    #pragma unroll
    for (int o=32;o;o>>=1) m = fmaxf(m, __shfl_xor(m, o));
    if (lane == 0) red[u][wv] = m;
    __syncthreads();
    m = fmaxf(fmaxf(red[u][0], red[u][1]), fmaxf(red[u][2], red[u][3]));
    float e = __expf(v - m);
    float sm = e;
    #pragma unroll
    for (int o=32;o;o>>=1) sm += __shfl_xor(sm, o);
    if (lane == 0) red[u][4+wv] = sm;
    __syncthreads();
    sm = red[u][4]+red[u][5]+red[u][6]+red[u][7];
    sw[u][t2] = e / sm;
    __syncthreads();
    int d = dch*256 + lane*4;
    const u16* xp = xb + (base + wv*64)*TD + d;
    f32x4 acc = {0,0,0,0};
    #pragma unroll 8
    for (int i=0; i<64; ++i){
      float w = sw[u][wv*64 + i];
      ushort4 uu = *(const ushort4*)(xp + (size_t)i*TD);
      acc[0] += w*b2f(uu.x); acc[1] += w*b2f(uu.y); acc[2] += w*b2f(uu.z); acc[3] += w*b2f(uu.w);
    }
    part[u][wv][lane] = acc;
    __syncthreads();
    if (wv == 0){
      f32x4 t0 = part[u][0][lane], t1 = part[u][1][lane], t2v = part[u][2][lane], t3 = part[u][3][lane];
      ushort4 o;
      o.x = f2b(t0[0]+t1[0]+t2v[0]+t3[0]);
      o.y = f2b(t0[1]+t1[1]+t2v[1]+t3[1]);
      o.z = f2b(t0[2]+t1[2]+t2v[2]+t3[2]);
      o.w = f2b(t0[3]+t1[3]+t2v[3]+t3[3]);
      *(ushort4*)(xbarb + ((size_t)b*TS + s)*TD + d) = o;
    }
    return;
  }
  int bi = blockIdx.x - 256;
  const u16 *A, *W; u16* O; int tr;
  if (bi < 64){ A=A1; W=W1; O=O1; tr=0; }
  else        { A=A2; W=W2; O=O2; tr=1; bi -= 64; }
  int by = bi >> 3, bx = bi & 7;
  int lane = tid & 63, wv = tid >> 6;
  int r15 = lane & 15, kg = lane >> 4;
  int wr = wv >> 2, wc = wv & 3;
  int m0 = by*128 + wr*64;
  int n0 = bx*128 + wc*32;
  const u16* ap = A + (size_t)(m0 + r15)*TD + kg*8;
  const u16* bp = W + (size_t)(n0 + r15)*TD + kg*8;
  f32x4 acc[4][2];
  #pragma unroll
  for (int i=0;i<4;i++){ f32x4 z={0,0,0,0}; acc[i][0]=z; acc[i][1]=z; }
  #pragma unroll 4
  for (int k0=0; k0<TD; k0+=32){
    bf16x8 b0 = *(const bf16x8*)(bp + k0);
    bf16x8 b1 = *(const bf16x8*)(bp + 16*TD + k0);
    bf16x8 a0 = *(const bf16x8*)(ap + k0);
    bf16x8 a1 = *(const bf16x8*)(ap + 16*TD + k0);
    bf16x8 a2 = *(const bf16x8*)(ap + 32*TD + k0);
    bf16x8 a3 = *(const bf16x8*)(ap + 48*TD + k0);
    acc[0][0] = __builtin_amdgcn_mfma_f32_16x16x32_bf16(a0, b0, acc[0][0], 0,0,0);
    acc[0][1] = __builtin_amdgcn_mfma_f32_16x16x32_bf16(a0, b1, acc[0][1], 0,0,0);
    acc[1][0] = __builtin_amdgcn_mfma_f32_16x16x32_bf16(a1, b0, acc[1][0], 0,0,0);
    acc[1][1] = __builtin_amdgcn_mfma_f32_16x16x32_bf16(a1, b1, acc[1][1], 0,0,0);
    acc[2][0] = __builtin_amdgcn_mfma_f32_16x16x32_bf16(a2, b0, acc[2][0], 0,0,0);
    acc[2][1] = __builtin_amdgcn_mfma_f32_16x16x32_bf16(a2, b1, acc[2][1], 0,0,0);
    acc[3][0] = __builtin_amdgcn_mfma_f32_16x16x32_bf16(a3, b0, acc[3][0], 0,0,0);
    acc[3][1] = __builtin_amdgcn_mfma_f32_16x16x32_bf16(a3, b1, acc[3][1], 0,0,0);
  }
  #pragma unroll
  for (int mf=0; mf<4; ++mf){
    #pragma unroll
    for (int nf=0; nf<2; ++nf){
      int n = n0 + nf*16 + r15;
      #pragma unroll
      for (int qq=0; qq<4; ++qq){
        float v = acc[mf][nf][qq];
        int m = m0 + mf*16 + kg*4 + qq;
        if (tr) O[(size_t)n*TD + m] = f2b(v);
        else    O[(size_t)m*TD + n] = f2b(v);
      }
    }
  }
}

// ---- xbar stage, all 3 outputs from xbar. grid (16,1,3), 512 thr: n-tile 64 ----
__global__ __launch_bounds__(512) void k_xbar3(const u16* __restrict__ xbarb,
                                               const u16* __restrict__ Wv, const u16* __restrict__ WdT,
                                               const u16* __restrict__ We,
                                               float* __restrict__ memo, u16* __restrict__ rkb,
                                               u16* __restrict__ rvT){
  int z = blockIdx.z;
  const u16* W = (z==0) ? Wv : (z==1) ? WdT : We;
  int tid = threadIdx.x, lane = tid & 63, wv = tid >> 6;
  int r15 = lane & 15, kg = lane >> 4;
  int wr = wv >> 2, wc = wv & 3;
  int n0 = blockIdx.x*64 + wc*16;
  const u16* ap = xbarb + (size_t)(wr*64 + r15)*TD + kg*8;
  const u16* bp = W + (size_t)(n0 + r15)*TD + kg*8;
  f32x4 acc[4];
  #pragma unroll
  for (int i=0;i<4;i++){ f32x4 zz={0,0,0,0}; acc[i]=zz; }
  #pragma unroll 4
  for (int k0=0; k0<TD; k0+=32){
    bf16x8 b0 = *(const bf16x8*)(bp + k0);
    bf16x8 a0 = *(const bf16x8*)(ap + k0);
    bf16x8 a1 = *(const bf16x8*)(ap + 16*TD + k0);
    bf16x8 a2 = *(const bf16x8*)(ap + 32*TD + k0);
    bf16x8 a3 = *(const bf16x8*)(ap + 48*TD + k0);
    acc[0] = __builtin_amdgcn_mfma_f32_16x16x32_bf16(a0, b0, acc[0], 0,0,0);
    acc[1] = __builtin_amdgcn_mfma_f32_16x16x32_bf16(a1, b0, acc[1], 0,0,0);
    acc[2] = __builtin_amdgcn_mfma_f32_16x16x32_bf16(a2, b0, acc[2], 0,0,0);
    acc[3] = __builtin_amdgcn_mfma_f32_16x16x32_bf16(a3, b0, acc[3], 0,0,0);
  }
  #pragma unroll
  for (int mf=0; mf<4; ++mf){
    int n = n0 + r15;
    #pragma unroll
    for (int qq=0; qq<4; ++qq){
      float v = acc[mf][qq];
      int m = wr*64 + mf*16 + kg*4 + qq;
      if (z == 0)      memo[(size_t)m*TD + n] = v;
      else if (z == 1) rkb[(size_t)m*TD + n] = f2b(v);
      else             rvT[((size_t)(m>>5)*TD + n)*TS + (m&31)] = f2b(v);
    }
  }
}

// ---- read-attention weights: QK^T (MFMA) + masked softmax -> normalized P [BT][32] bf16 ----
__global__ __launch_bounds__(256) void k_pattn(const u16* __restrict__ xb, const u16* __restrict__ rkb,
                                               u16* __restrict__ P){
  int tid = threadIdx.x, lane = tid & 63, wv = tid >> 6;
  long bt0 = (long)blockIdx.x * 64;
  int b = (int)(bt0 >> 13);
  int smin = (int)((bt0 & (TT-1)) >> 8);
  int r15 = lane & 15, kg = lane >> 4;

  long tw = bt0 + wv*16;
  const u16* ap  = xb  + (size_t)(tw + r15)*TD + kg*8;
  const u16* bp0 = rkb + ((size_t)(b*TS + r15))*TD + kg*8;
  const u16* bp1 = rkb + ((size_t)(b*TS + 16 + r15))*TD + kg*8;
  f32x4 p0 = {0,0,0,0}, p1 = {0,0,0,0};
  #pragma unroll 4
  for (int ks=0; ks<32; ++ks){
    bf16x8 a  = *(const bf16x8*)(ap  + ks*32);
    bf16x8 b0 = *(const bf16x8*)(bp0 + ks*32);
    bf16x8 b1 = *(const bf16x8*)(bp1 + ks*32);
    p0 = __builtin_amdgcn_mfma_f32_16x16x32_bf16(a, b0, p0, 0,0,0);
    p1 = __builtin_amdgcn_mfma_f32_16x16x32_bf16(a, b1, p1, 0,0,0);
  }
  bool msk0 = (r15 < smin), msk1 = (16 + r15 < smin);
  #pragma unroll
  for (int q=0;q<4;q++){
    float l0 = msk0 ? -1e30f : p0[q];
    float l1 = msk1 ? -1e30f : p1[q];
    float mx = fmaxf(l0, l1);
    #pragma unroll
    for (int o=1;o<16;o<<=1) mx = fmaxf(mx, __shfl_xor(mx, o));
    float e0 = msk0 ? 0.f : __expf(l0 - mx);
    float e1 = msk1 ? 0.f : __expf(l1 - mx);
    float smv = e0 + e1;
    #pragma unroll
    for (int o=1;o<16;o<<=1) smv += __shfl_xor(smv, o);
    float rs = 1.f/smv;
    long trow = tw + 4*kg + q;
    P[trow*TS + r15]      = f2b(e0*rs);
    P[trow*TS + 16 + r15] = f2b(e1*rs);
  }
}

// ---- big MFMA GEMM: C[32768,1024] = A @ W^T  (R12-measured: 8 waves, BK=64,
// 2-slot dbuf, 0 conflicts, 90.7us). SIG: global-P epilogue. ----
template<bool SIG>
__global__ __launch_bounds__(512, 2) void k_gemm(const u16* __restrict__ A, const u16* __restrict__ Bw,
                                                 const float* __restrict__ bias, void* __restrict__ Cp,
                                                 const u16* __restrict__ P, const u16* __restrict__ rvT){
  __shared__ __align__(16) char sL[131072];
  int tid = threadIdx.x, lane = tid & 63, wv = tid >> 6;
  int bid = blockIdx.x;
  int wg = ((bid & 7) << 6) | (bid >> 3);   // XCD swizzle, 512 % 8 == 0 -> bijective
  int nt = wg & 3, mt = wg >> 2;
  int m0 = mt*256, n0 = nt*256;
  int wr = wv >> 2, wc = wv & 3;
  int r15 = lane & 15, kg = lane >> 4;

  int ard[8], brd[4];
  #pragma unroll
  for (int i=0;i<8;i++){ int row = wr*128 + i*16 + r15; ard[i] = row*128 + ((kg ^ (row&7))<<4); }
  #pragma unroll
  for (int j=0;j<4;j++){ int row = wc*64  + j*16 + r15; brd[j] = row*128 + ((kg ^ (row&7))<<4); }

  const u16* asrc[4]; const u16* bsrc[4]; int ldst[4];
  #pragma unroll
  for (int r=0;r<4;r++){
    int Sp  = r*512 + tid;
    int row = Sp >> 3;
    int kq  = (Sp & 7) ^ (row & 7);
    asrc[r] = A  + (size_t)(m0 + row)*TD + kq*8;
    bsrc[r] = Bw + (size_t)(n0 + row)*TD + kq*8;
    ldst[r] = Sp*16;
  }

  f32x4 acc[8][4];
  #pragma unroll
  for (int i=0;i<8;i++){
    #pragma unroll
    for (int j=0;j<4;j++){ f32x4 z = {0,0,0,0}; acc[i][j] = z; }
  }

  auto stage = [&](int t){
    char* slot = sL + (size_t)(t&1)*65536;
    int k0 = t*64;
    #pragma unroll
    for (int r=0;r<4;r++) gll16(asrc[r] + k0, slot + ldst[r]);
    #pragma unroll
    for (int r=0;r<4;r++) gll16(bsrc[r] + k0, slot + 32768 + ldst[r]);
  };

  auto compute = [&](int t){
    const char* sa = sL + (size_t)(t&1)*65536;
    const char* sb = sa + 32768;
    bf16x8 bfg[4], af[4];
    #pragma unroll
    for (int j=0;j<4;j++) bfg[j] = *(const bf16x8*)(sb + brd[j]);
    #pragma unroll
    for (int i=0;i<4;i++) af[i] = *(const bf16x8*)(sa + ard[i]);
    LGKM0();
    __builtin_amdgcn_sched_barrier(0);
    __builtin_amdgcn_s_setprio(1);
    #pragma unroll
    for (int i=0;i<4;i++){
      #pragma unroll
      for (int j=0;j<4;j++)
        acc[i][j] = __builtin_amdgcn_mfma_f32_16x16x32_bf16(af[i], bfg[j], acc[i][j], 0,0,0);
    }
    __builtin_amdgcn_s_setprio(0);
    bf16x8 af2[4];
    #pragma unroll
    for (int i=0;i<4;i++) af2[i] = *(const bf16x8*)(sa + (ard[4+i]));
    LGKM0();
    __builtin_amdgcn_sched_barrier(0);
    __builtin_amdgcn_s_setprio(1);
    #pragma unroll
    for (int i=0;i<4;i++){
      #pragma unroll
      for (int j=0;j<4;j++)
        acc[4+i][j] = __builtin_amdgcn_mfma_f32_16x16x32_bf16(af2[i], bfg[j], acc[4+i][j], 0,0,0);
    }
    __builtin_amdgcn_s_setprio(0);
    bf16x8 bfh[4], ag[4];
    #pragma unroll
    for (int j=0;j<4;j++) bfh[j] = *(const bf16x8*)(sb + (brd[j]^64));
    #pragma unroll
    for (int i=0;i<4;i++) ag[i] = *(const bf16x8*)(sa + (ard[i]^64));
    LGKM0();
    __builtin_amdgcn_sched_barrier(0);
    __builtin_amdgcn_s_setprio(1);
    #pragma unroll
    for (int i=0;i<4;i++){
      #pragma unroll
      for (int j=0;j<4;j++)
        acc[i][j] = __builtin_amdgcn_mfma_f32_16x16x32_bf16(ag[i], bfh[j], acc[i][j], 0,0,0);
    }
    __builtin_amdgcn_s_setprio(0);
    bf16x8 ag2[4];
    #pragma unroll
    for (int i=0;i<4;i++) ag2[i] = *(const bf16x8*)(sa + (ard[4+i]^64));
    LGKM0();
    __builtin_amdgcn_sched_barrier(0);
    __builtin_amdgcn_s_setprio(1);
    #pragma unroll
    for (int i=0;i<4;i++){
      #pragma unroll
      for (int j=0;j<4;j++)
        acc[4+i][j] = __builtin_amdgcn_mfma_f32_16x16x32_bf16(ag2[i], bfh[j], acc[4+i][j], 0,0,0);
    }
    __builtin_amdgcn_s_setprio(0);
  };

  stage(0);
  for (int t=0; t<16; ++t){
    if (t > 0) __builtin_amdgcn_s_barrier();
    if (t < 15){
      stage(t+1);
      VMWAIT(8);
    } else {
      VMWAIT(0);
    }
    __builtin_amdgcn_s_barrier();
    compute(t);
  }

  // epilogue: C row = kg*4+q, col = r15
  if (SIG){
    int b = m0 >> 13;
    bf16x8 vfrag[4];
    #pragma unroll
    for (int j=0;j<4;j++){
      int n = n0 + wc*64 + j*16 + r15;
      vfrag[j] = *(const bf16x8*)(rvT + ((size_t)b*TD + n)*TS + kg*8);
    }
    #pragma unroll
    for (int i=0;i<8;i++){
      int tokbase = m0 + wr*128 + i*16;
      bf16x8 pfrag = *(const bf16x8*)(P + (size_t)(tokbase + r15)*TS + kg*8);
      f32x4 rd[4];
      #pragma unroll
      for (int j=0;j<4;j++){
        f32x4 z = {0,0,0,0};
        rd[j] = __builtin_amdgcn_mfma_f32_16x16x32_bf16(pfrag, vfrag[j], z, 0,0,0);
      }
      int mrow = tokbase + kg*4;
      #pragma unroll
      for (int j=0;j<4;j++){
        int n = n0 + wc*64 + j*16 + r15;
        float bj = bias[n];
        #pragma unroll
        for (int q=0;q<4;q++){
          float g = 1.f/(1.f + __expf(-(acc[i][j][q] + bj)));
          size_t idx = (size_t)(mrow + q)*TD + n;
          float xv = b2f(A[idx]);   // A == xb
          ((u16*)Cp)[idx] = f2b(xv + g*rd[j][q]);
        }
      }
    }
  } else {
    #pragma unroll
    for (int i=0;i<8;i++){
      int mrow = m0 + wr*128 + i*16 + kg*4;
      #pragma unroll
      for (int j=0;j<4;j++){
        int n = n0 + wc*64 + j*16 + r15;
        #pragma unroll
        for (int q=0;q<4;q++){
          size_t idx = (size_t)(mrow + q)*TD + n;
          ((float*)Cp)[idx] = acc[i][j][q];
        }
      }
    }
  }
}

extern "C" void kernel_launch(void* const* d_in, const int* in_sizes, int n_in,
                              void* d_out, int out_size, void* d_ws, size_t ws_size,
                              hipStream_t stream){
  const float* x   = (const float*)d_in[0];
  const float* gw  = (const float*)d_in[1];
  const float* gb  = (const float*)d_in[2];
  const float* rqw = (const float*)d_in[3];
  const float* rkw = (const float*)d_in[4];
  const float* rvw = (const float*)d_in[5];
  const float* ow  = (const float*)d_in[6];
  const float* ms  = (const float*)d_in[7];
  const float* wqw = (const float*)d_in[8];
  const float* wkw = (const float*)d_in[9];
  const float* wvw = (const float*)d_in[10];
  float* out = (float*)d_out;
  float* mem_out = out + (size_t)BT*TD;   // byte offset 134217728

  // d_out scratch (dead before final GEMM overwrites [0,128MB)):
  char* o = (char*)d_out;
  u16* xb    = (u16*)o;                  // 64MB
  u16* Pb    = (u16*)(o + 67108864);     // 2MB
  u16* gwb   = (u16*)(o + 69206016);     // 2MB
  u16* wvwb  = (u16*)(o + 71303168);     // 2MB
  u16* rkwb  = (u16*)(o + 73400320);     // 2MB
  u16* rvwb  = (u16*)(o + 75497472);     // 2MB
  u16* xbarb = (u16*)(o + 79757312);     // 256KB
  u16* rvT   = (u16*)(o + 80281600);     // 256KB
  u16* WvT   = (u16*)(o + 84934656);     // 2MB
  u16* WrqT  = (u16*)(o + 87031808);     // 2MB
  u16* qbb   = (u16*)(o + 89128960);     // 64KB (q' bf16 [32][1024])
  u16* WkT   = (u16*)(o + 91226112);     // 2MB
  u16* We    = (u16*)(o + 95420416);     // 2MB
  u16* WdT   = (u16*)(o + 97517568);     // 2MB
  u16* WrkT  = (u16*)(o + 103809024);    // 2MB
  u16* WgT   = (u16*)(o + 105906176);    // 2MB

  char* w = (char*)d_ws;
  u16*   gy    = (u16*)(w);                    // 64MB (y = x + g*read)
  float* wqkb  = (float*)(w + 67108864);       // 128KB
  float* qkp   = (float*)(w + 67239936);       // 128KB (qk f32 [32][1024])
  u16*   rkb   = (u16*)(w + 67502080);         // 256KB
  u16*   owb   = (u16*)(w + 68288512);         // 2MB

  // 1. transposes: WvT,WrqT,WkT,WrkT ; q' = bf16(ms @ Wq^T)
  k_tran<<<dim3(16,16,5),256,0,stream>>>(wvw, rqw, wkw, rkw, ms, wqw,
                                         WvT, WrqT, WkT, WrkT, qbb);
  // 2. WgT = (scale*Wrk^T@Wrq)^T ; qkp = scale * q' @ Wk
  k_smmw2<<<dim3(8,8,2),512,0,stream>>>(WrkT, WrqT, WgT, qbb, WkT, qkp);
  // 3. xb = bf16(x); wqk = x . qkp[seg]; + convert 5 weight matrices
  k_convdot<<<7168,256,0,stream>>>(x, qkp, xb, wqkb,
                                   gw, ow, wvw, rkw, rvw,
                                   gwb, owb, wvwb, rkwb, rvwb);
  // 4. merged: xbar = softmax(wqk).x  +  {We = Wrv@Wv ; WdT = (Wv^T@Wg)^T}
  k_wattn_smm<<<384,512,0,stream>>>(wqkb, xb, xbarb,
                                    rvwb, WvT, We,
                                    WvT, WgT, WdT);
  // 5. mem_out = xbar@Wv^T (f32); rk~ = xbar@Wd (bf16); rvT = (xbar@We^T)^T
  k_xbar3<<<dim3(16,1,3),512,0,stream>>>(xbarb, wvwb, WdT, We, mem_out, rkb, rvT);
  // 6. P = softmax(mask(xb @ rk~^T)) normalized, bf16 [BT][32]
  k_pattn<<<512,256,0,stream>>>(xb, rkb, Pb);
  // 7. y = x + sigmoid(x@gate_w^T + gb) * (P @ rvT)
  k_gemm<true><<<512,512,0,stream>>>(xb, gwb, gb, gy, Pb, rvT);
  // 8. out = y @ output_w^T
  k_gemm<false><<<512,512,0,stream>>>(gy, owb, nullptr, d_out, nullptr, nullptr);
}

// Round 18
// 388.738 us; speedup vs baseline: 1.0321x; 1.0321x over previous
//
#include <hip/hip_runtime.h>
#include <stdint.h>

// Problem constants
#define TB 4
#define TT 8192
#define TD 1024
#define TS 32
#define TL 256
#define BT 32768   // TB*TT

typedef unsigned short u16;
typedef __bf16 bf16x8 __attribute__((ext_vector_type(8)));
typedef float f32x4 __attribute__((ext_vector_type(4)));

typedef uint32_t u32_g __attribute__((address_space(1)));
typedef uint32_t u32_l __attribute__((address_space(3)));

#define VMWAIT(N) asm volatile("s_waitcnt vmcnt(" #N ")" ::: "memory")
#define LGKM0()   asm volatile("s_waitcnt lgkmcnt(0)" ::: "memory")

__device__ __forceinline__ u16 f2b(float f){
  union { float f; uint32_t u; } a; a.f = f;
  uint32_t r = a.u + 0x7FFFu + ((a.u >> 16) & 1u);
  return (u16)(r >> 16);
}
__device__ __forceinline__ float b2f(u16 u){
  union { uint32_t u; float f; } a; a.u = ((uint32_t)u) << 16;
  return a.f;
}
__device__ __forceinline__ void gll16(const void* g, void* l){
  __builtin_amdgcn_global_load_lds((const u32_g*)g, (u32_l*)l, 16, 0, 0);
}

// ---- transpose+convert f32 [1024][1024] -> bf16 T[j][i] (z=0..4); z=5: ms -> bf16 ----
__global__ void k_tran(const float* __restrict__ w0, const float* __restrict__ w1,
                       const float* __restrict__ w2, const float* __restrict__ w3,
                       const float* __restrict__ w4, const float* __restrict__ ms,
                       u16* __restrict__ t0, u16* __restrict__ t1,
                       u16* __restrict__ t2, u16* __restrict__ t3,
                       u16* __restrict__ t4, u16* __restrict__ msb){
  int tid = threadIdx.x, z = blockIdx.z;
  if (z == 5){
    int i = (blockIdx.y*16 + blockIdx.x)*256 + tid;   // float4 index
    if (i < 8192){
      float4 v = ((const float4*)ms)[i];
      ushort4 u; u.x=f2b(v.x); u.y=f2b(v.y); u.z=f2b(v.z); u.w=f2b(v.w);
      ((ushort4*)msb)[i] = u;
    }
    return;
  }
  const float* src = (z==0)?w0:(z==1)?w1:(z==2)?w2:(z==3)?w3:w4;
  u16* dst = (z==0)?t0:(z==1)?t1:(z==2)?t2:(z==3)?t3:t4;
  __shared__ float sT[64][65];
  int r0 = blockIdx.y*64, c0 = blockIdx.x*64;
  int lr = tid >> 2, lc = (tid & 3)*16;
  #pragma unroll
  for (int j=0; j<4; ++j){
    float4 v = *(const float4*)(src + (size_t)(r0+lr)*TD + c0 + lc + j*4);
    sT[lr][lc+j*4+0]=v.x; sT[lr][lc+j*4+1]=v.y; sT[lr][lc+j*4+2]=v.z; sT[lr][lc+j*4+3]=v.w;
  }
  __syncthreads();
  int oc = tid >> 2, orh = (tid & 3)*16;
  #pragma unroll
  for (int j=0; j<4; ++j){
    ushort4 u;
    u.x = f2b(sT[orh+j*4+0][oc]);
    u.y = f2b(sT[orh+j*4+1][oc]);
    u.z = f2b(sT[orh+j*4+2][oc]);
    u.w = f2b(sT[orh+j*4+3][oc]);
    *(ushort4*)(dst + (size_t)(c0+oc)*TD + r0 + orh + j*4) = u;
  }
}

// ---- weight GEMM: C[1024,1024] = A @ W^T (A,W bf16 [rows][K] k-contig), 2 config slots ----
__global__ __launch_bounds__(512) void k_smmw(
    const u16* __restrict__ A0, const u16* __restrict__ W0, u16* __restrict__ O0, int tr0, float s0,
    const u16* __restrict__ A1, const u16* __restrict__ W1, u16* __restrict__ O1, int tr1, float s1){
  const u16 *A, *W; u16* O; int tr; float sc;
  if (blockIdx.z == 0){ A=A0; W=W0; O=O0; tr=tr0; sc=s0; }
  else                { A=A1; W=W1; O=O1; tr=tr1; sc=s1; }
  int tid = threadIdx.x, lane = tid & 63, wv = tid >> 6;
  int r15 = lane & 15, kg = lane >> 4;
  int wr = wv >> 2, wc = wv & 3;
  int m0 = blockIdx.y*128 + wr*64;
  int n0 = blockIdx.x*128 + wc*32;
  const u16* ap = A + (size_t)(m0 + r15)*TD + kg*8;
  const u16* bp = W + (size_t)(n0 + r15)*TD + kg*8;
  f32x4 acc[4][2];
  #pragma unroll
  for (int i=0;i<4;i++){ f32x4 z={0,0,0,0}; acc[i][0]=z; acc[i][1]=z; }
  #pragma unroll 2
  for (int k0=0; k0<TD; k0+=32){
    bf16x8 b0 = *(const bf16x8*)(bp + k0);
    bf16x8 b1 = *(const bf16x8*)(bp + 16*TD + k0);
    bf16x8 a0 = *(const bf16x8*)(ap + k0);
    bf16x8 a1 = *(const bf16x8*)(ap + 16*TD + k0);
    bf16x8 a2 = *(const bf16x8*)(ap + 32*TD + k0);
    bf16x8 a3 = *(const bf16x8*)(ap + 48*TD + k0);
    acc[0][0] = __builtin_amdgcn_mfma_f32_16x16x32_bf16(a0, b0, acc[0][0], 0,0,0);
    acc[0][1] = __builtin_amdgcn_mfma_f32_16x16x32_bf16(a0, b1, acc[0][1], 0,0,0);
    acc[1][0] = __builtin_amdgcn_mfma_f32_16x16x32_bf16(a1, b0, acc[1][0], 0,0,0);
    acc[1][1] = __builtin_amdgcn_mfma_f32_16x16x32_bf16(a1, b1, acc[1][1], 0,0,0);
    acc[2][0] = __builtin_amdgcn_mfma_f32_16x16x32_bf16(a2, b0, acc[2][0], 0,0,0);
    acc[2][1] = __builtin_amdgcn_mfma_f32_16x16x32_bf16(a2, b1, acc[2][1], 0,0,0);
    acc[3][0] = __builtin_amdgcn_mfma_f32_16x16x32_bf16(a3, b0, acc[3][0], 0,0,0);
    acc[3][1] = __builtin_amdgcn_mfma_f32_16x16x32_bf16(a3, b1, acc[3][1], 0,0,0);
  }
  #pragma unroll
  for (int mf=0; mf<4; ++mf){
    #pragma unroll
    for (int nf=0; nf<2; ++nf){
      int n = n0 + nf*16 + r15;
      #pragma unroll
      for (int qq=0; qq<4; ++qq){
        float v = acc[mf][nf][qq]*sc;
        int m = m0 + mf*16 + kg*4 + qq;
        if (tr) O[(size_t)n*TD + m] = f2b(v);
        else    O[(size_t)m*TD + n] = f2b(v);
      }
    }
  }
}

// ---- qk partials: qkp[kh][32][1024] = scale * ms @ Wz over K-half kh. grid (8,2), 512 thr ----
__global__ __launch_bounds__(512) void k_qk32(const u16* __restrict__ msb, const u16* __restrict__ WzT,
                                              float* __restrict__ qkp){
  int tid = threadIdx.x, lane = tid & 63, wv = tid >> 6;
  int r15 = lane & 15, kg = lane >> 4;
  int n0 = blockIdx.x*128 + wv*16;
  int kbase = blockIdx.y*512;
  const u16* ap = msb + (size_t)r15*TD + kbase + kg*8;
  const u16* bp = WzT + (size_t)(n0 + r15)*TD + kbase + kg*8;
  f32x4 a0 = {0,0,0,0}, a1 = {0,0,0,0};
  #pragma unroll 4
  for (int k0=0; k0<512; k0+=32){
    bf16x8 b  = *(const bf16x8*)(bp + k0);
    bf16x8 x0 = *(const bf16x8*)(ap + k0);
    bf16x8 x1 = *(const bf16x8*)(ap + 16*TD + k0);
    a0 = __builtin_amdgcn_mfma_f32_16x16x32_bf16(x0, b, a0, 0,0,0);
    a1 = __builtin_amdgcn_mfma_f32_16x16x32_bf16(x1, b, a1, 0,0,0);
  }
  const float sc = 1.0f/32.0f;
  float* o = qkp + (size_t)blockIdx.y*32768;
  #pragma unroll
  for (int qq=0; qq<4; ++qq){
    o[(size_t)(kg*4 + qq)*TD + n0 + r15]      = a0[qq]*sc;
    o[(size_t)(16 + kg*4 + qq)*TD + n0 + r15] = a1[qq]*sc;
  }
}

// ---- merged: blocks [0,2048) = conv_dot; blocks [2048,7168) = convert 5 weights -> bf16 ----
__global__ void k_convdot(const float* __restrict__ x, const float* __restrict__ qkp,
                          u16* __restrict__ xb, float* __restrict__ wqk,
                          const float* __restrict__ s0, const float* __restrict__ s1,
                          const float* __restrict__ s2, const float* __restrict__ s3,
                          const float* __restrict__ s4,
                          u16* __restrict__ d0, u16* __restrict__ d1,
                          u16* __restrict__ d2, u16* __restrict__ d3,
                          u16* __restrict__ d4){
  int tid = threadIdx.x;
  if (blockIdx.x >= 2048){
    int i = (blockIdx.x - 2048)*256 + tid;
    int mi = i >> 18, j = i & 262143;
    const float* src; u16* dst;
    if      (mi == 0){ src = s0; dst = d0; }
    else if (mi == 1){ src = s1; dst = d1; }
    else if (mi == 2){ src = s2; dst = d2; }
    else if (mi == 3){ src = s3; dst = d3; }
    else             { src = s4; dst = d4; }
    float4 v = ((const float4*)src)[j];
    ushort4 u; u.x=f2b(v.x); u.y=f2b(v.y); u.z=f2b(v.z); u.w=f2b(v.w);
    ((ushort4*)dst)[j] = u;
    return;
  }
  int lane = tid & 63, wv = tid >> 6;
  long bt0 = (long)blockIdx.x * 16;
  int sseg = (int)((bt0 & (TT-1)) >> 8);
  float qv[16];
  #pragma unroll
  for (int i=0;i<4;i++){
    const float* qp = qkp + (size_t)sseg*TD + i*256 + lane*4;
    float4 ta = *(const float4*)qp;
    float4 tb = *(const float4*)(qp + 32768);
    qv[i*4+0]=ta.x+tb.x; qv[i*4+1]=ta.y+tb.y; qv[i*4+2]=ta.z+tb.z; qv[i*4+3]=ta.w+tb.w;
  }
  for (int tok = wv; tok < 16; tok += 4){
    long bt = bt0 + tok;
    const float* xr = x + bt*TD;
    float dot = 0.f;
    #pragma unroll
    for (int i=0;i<4;i++){
      float4 t = *(const float4*)(xr + i*256 + lane*4);
      ushort4 u; u.x=f2b(t.x); u.y=f2b(t.y); u.z=f2b(t.z); u.w=f2b(t.w);
      *(ushort4*)(xb + bt*TD + i*256 + lane*4) = u;
      dot += t.x*qv[i*4] + t.y*qv[i*4+1] + t.z*qv[i*4+2] + t.w*qv[i*4+3];
    }
    #pragma unroll
    for (int o=32;o;o>>=1) dot += __shfl_xor(dot, o);
    if (lane == 0) wqk[bt] = dot;
  }
}

// ---- merged: blocks [0,256) = wattn (2 units of 256 thr); [256,384) = smmw (We, WdT) ----
__global__ __launch_bounds__(512) void k_wattn_smm(
    const float* __restrict__ wqk, const u16* __restrict__ xb, u16* __restrict__ xbarb,
    const u16* __restrict__ A1, const u16* __restrict__ W1, u16* __restrict__ O1,  // We (tr0)
    const u16* __restrict__ A2, const u16* __restrict__ W2, u16* __restrict__ O2){ // WdT (tr1)
  __shared__ float sw[2][TL];
  __shared__ float red[2][8];
  __shared__ f32x4 part[2][4][64];
  int tid = threadIdx.x;
  if (blockIdx.x < 256){
    int u = tid >> 8;
    int unit = blockIdx.x*2 + u;
    int bs = unit >> 2, dch = unit & 3;
    int b = bs >> 5, s = bs & 31;
    int t2 = tid & 255, lane = t2 & 63, wv = t2 >> 6;
    long base = (long)b*TT + (long)s*TL;
    float v = wqk[base + t2];
    float m = v;
    #pragma unroll
    for (int o=32;o;o>>=1) m = fmaxf(m, __shfl_xor(m, o));
    if (lane == 0) red[u][wv] = m;
    __syncthreads();
    m = fmaxf(fmaxf(red[u][0], red[u][1]), fmaxf(red[u][2], red[u][3]));
    float e = __expf(v - m);
    float sm = e;
    #pragma unroll
    for (int o=32;o;o>>=1) sm += __shfl_xor(sm, o);
    if (lane == 0) red[u][4+wv] = sm;
    __syncthreads();
    sm = red[u][4]+red[u][5]+red[u][6]+red[u][7];
    sw[u][t2] = e / sm;
    __syncthreads();
    int d = dch*256 + lane*4;
    const u16* xp = xb + (base + wv*64)*TD + d;
    f32x4 acc = {0,0,0,0};
    #pragma unroll 8
    for (int i=0; i<64; ++i){
      float w = sw[u][wv*64 + i];
      ushort4 uu = *(const ushort4*)(xp + (size_t)i*TD);
      acc[0] += w*b2f(uu.x); acc[1] += w*b2f(uu.y); acc[2] += w*b2f(uu.z); acc[3] += w*b2f(uu.w);
    }
    part[u][wv][lane] = acc;
    __syncthreads();
    if (wv == 0){
      f32x4 t0 = part[u][0][lane], t1 = part[u][1][lane], t2v = part[u][2][lane], t3 = part[u][3][lane];
      ushort4 o;
      o.x = f2b(t0[0]+t1[0]+t2v[0]+t3[0]);
      o.y = f2b(t0[1]+t1[1]+t2v[1]+t3[1]);
      o.z = f2b(t0[2]+t1[2]+t2v[2]+t3[2]);
      o.w = f2b(t0[3]+t1[3]+t2v[3]+t3[3]);
      *(ushort4*)(xbarb + ((size_t)b*TS + s)*TD + d) = o;
    }
    return;
  }
  // smmw part
  int bi = blockIdx.x - 256;
  const u16 *A, *W; u16* O; int tr;
  if (bi < 64){ A=A1; W=W1; O=O1; tr=0; }
  else        { A=A2; W=W2; O=O2; tr=1; bi -= 64; }
  int by = bi >> 3, bx = bi & 7;
  int lane = tid & 63, wv = tid >> 6;
  int r15 = lane & 15, kg = lane >> 4;
  int wr = wv >> 2, wc = wv & 3;
  int m0 = by*128 + wr*64;
  int n0 = bx*128 + wc*32;
  const u16* ap = A + (size_t)(m0 + r15)*TD + kg*8;
  const u16* bp = W + (size_t)(n0 + r15)*TD + kg*8;
  f32x4 acc[4][2];
  #pragma unroll
  for (int i=0;i<4;i++){ f32x4 z={0,0,0,0}; acc[i][0]=z; acc[i][1]=z; }
  #pragma unroll 2
  for (int k0=0; k0<TD; k0+=32){
    bf16x8 b0 = *(const bf16x8*)(bp + k0);
    bf16x8 b1 = *(const bf16x8*)(bp + 16*TD + k0);
    bf16x8 a0 = *(const bf16x8*)(ap + k0);
    bf16x8 a1 = *(const bf16x8*)(ap + 16*TD + k0);
    bf16x8 a2 = *(const bf16x8*)(ap + 32*TD + k0);
    bf16x8 a3 = *(const bf16x8*)(ap + 48*TD + k0);
    acc[0][0] = __builtin_amdgcn_mfma_f32_16x16x32_bf16(a0, b0, acc[0][0], 0,0,0);
    acc[0][1] = __builtin_amdgcn_mfma_f32_16x16x32_bf16(a0, b1, acc[0][1], 0,0,0);
    acc[1][0] = __builtin_amdgcn_mfma_f32_16x16x32_bf16(a1, b0, acc[1][0], 0,0,0);
    acc[1][1] = __builtin_amdgcn_mfma_f32_16x16x32_bf16(a1, b1, acc[1][1], 0,0,0);
    acc[2][0] = __builtin_amdgcn_mfma_f32_16x16x32_bf16(a2, b0, acc[2][0], 0,0,0);
    acc[2][1] = __builtin_amdgcn_mfma_f32_16x16x32_bf16(a2, b1, acc[2][1], 0,0,0);
    acc[3][0] = __builtin_amdgcn_mfma_f32_16x16x32_bf16(a3, b0, acc[3][0], 0,0,0);
    acc[3][1] = __builtin_amdgcn_mfma_f32_16x16x32_bf16(a3, b1, acc[3][1], 0,0,0);
  }
  #pragma unroll
  for (int mf=0; mf<4; ++mf){
    #pragma unroll
    for (int nf=0; nf<2; ++nf){
      int n = n0 + nf*16 + r15;
      #pragma unroll
      for (int qq=0; qq<4; ++qq){
        float v = acc[mf][nf][qq];
        int m = m0 + mf*16 + kg*4 + qq;
        if (tr) O[(size_t)n*TD + m] = f2b(v);
        else    O[(size_t)m*TD + n] = f2b(v);
      }
    }
  }
}

// ---- xbar stage, all 3 outputs from xbar in one launch. grid (8,1,3), 512 thr ----
__global__ __launch_bounds__(512) void k_xbar3(const u16* __restrict__ xbarb,
                                               const u16* __restrict__ Wv, const u16* __restrict__ WdT,
                                               const u16* __restrict__ We,
                                               float* __restrict__ memo, u16* __restrict__ rkb,
                                               u16* __restrict__ rvT){
  int z = blockIdx.z;
  const u16* W = (z==0) ? Wv : (z==1) ? WdT : We;
  int tid = threadIdx.x, lane = tid & 63, wv = tid >> 6;
  int r15 = lane & 15, kg = lane >> 4;
  int wr = wv >> 2, wc = wv & 3;
  int n0 = blockIdx.x*128 + wc*32;
  const u16* ap = xbarb + (size_t)(wr*64 + r15)*TD + kg*8;
  const u16* bp = W + (size_t)(n0 + r15)*TD + kg*8;
  f32x4 acc[4][2];
  #pragma unroll
  for (int i=0;i<4;i++){ f32x4 zz={0,0,0,0}; acc[i][0]=zz; acc[i][1]=zz; }
  #pragma unroll 2
  for (int k0=0; k0<TD; k0+=32){
    bf16x8 b0 = *(const bf16x8*)(bp + k0);
    bf16x8 b1 = *(const bf16x8*)(bp + 16*TD + k0);
    bf16x8 a0 = *(const bf16x8*)(ap + k0);
    bf16x8 a1 = *(const bf16x8*)(ap + 16*TD + k0);
    bf16x8 a2 = *(const bf16x8*)(ap + 32*TD + k0);
    bf16x8 a3 = *(const bf16x8*)(ap + 48*TD + k0);
    acc[0][0] = __builtin_amdgcn_mfma_f32_16x16x32_bf16(a0, b0, acc[0][0], 0,0,0);
    acc[0][1] = __builtin_amdgcn_mfma_f32_16x16x32_bf16(a0, b1, acc[0][1], 0,0,0);
    acc[1][0] = __builtin_amdgcn_mfma_f32_16x16x32_bf16(a1, b0, acc[1][0], 0,0,0);
    acc[1][1] = __builtin_amdgcn_mfma_f32_16x16x32_bf16(a1, b1, acc[1][1], 0,0,0);
    acc[2][0] = __builtin_amdgcn_mfma_f32_16x16x32_bf16(a2, b0, acc[2][0], 0,0,0);
    acc[2][1] = __builtin_amdgcn_mfma_f32_16x16x32_bf16(a2, b1, acc[2][1], 0,0,0);
    acc[3][0] = __builtin_amdgcn_mfma_f32_16x16x32_bf16(a3, b0, acc[3][0], 0,0,0);
    acc[3][1] = __builtin_amdgcn_mfma_f32_16x16x32_bf16(a3, b1, acc[3][1], 0,0,0);
  }
  #pragma unroll
  for (int mf=0; mf<4; ++mf){
    #pragma unroll
    for (int nf=0; nf<2; ++nf){
      int n = n0 + nf*16 + r15;
      #pragma unroll
      for (int qq=0; qq<4; ++qq){
        float v = acc[mf][nf][qq];
        int m = wr*64 + mf*16 + kg*4 + qq;
        if (z == 0)      memo[(size_t)m*TD + n] = v;
        else if (z == 1) rkb[(size_t)m*TD + n] = f2b(v);
        else             rvT[((size_t)(m>>5)*TD + n)*TS + (m&31)] = f2b(v);
      }
    }
  }
}

// ---- big MFMA GEMM: C[32768,1024] = A @ W^T  (BK=64, 2-slot dbuf, 0 conflicts) ----
// SIG=true fuses read-attention in-kernel. P-waves balanced one-per-SIMD:
// {wv0,wv1,wv6,wv7} = (wr0,wc0),(wr0,wc1),(wr1,wc2),(wr1,wc3) -> SIMDs 0,1,2,3.
template<bool SIG>
__global__ __launch_bounds__(512, 2) void k_gemm(const u16* __restrict__ A, const u16* __restrict__ Bw,
                                                 const float* __restrict__ bias, void* __restrict__ Cp,
                                                 const u16* __restrict__ rkb, const u16* __restrict__ rvT){
  __shared__ __align__(16) char sL[131072];
  int tid = threadIdx.x, lane = tid & 63, wv = tid >> 6;
  int bid = blockIdx.x;
  int wg = ((bid & 7) << 6) | (bid >> 3);   // XCD swizzle, 512 % 8 == 0 -> bijective
  int nt = wg & 3, mt = wg >> 2;
  int m0 = mt*256, n0 = nt*256;
  int wr = wv >> 2, wc = wv & 3;
  int r15 = lane & 15, kg = lane >> 4;
  int smin = (m0 & (TT-1)) >> 8;            // block spans exactly one segment
  bool wcP = SIG && ((wr == 0) ? (wc < 2) : (wc >= 2));   // one P-wave per SIMD

  int ard[8], brd[4];
  #pragma unroll
  for (int i=0;i<8;i++){ int row = wr*128 + i*16 + r15; ard[i] = row*128 + ((kg ^ (row&7))<<4); }
  #pragma unroll
  for (int j=0;j<4;j++){ int row = wc*64  + j*16 + r15; brd[j] = row*128 + ((kg ^ (row&7))<<4); }

  const u16* asrc[4]; const u16* bsrc[4]; int ldst[4];
  #pragma unroll
  for (int r=0;r<4;r++){
    int Sp  = r*512 + tid;
    int row = Sp >> 3;
    int kq  = (Sp & 7) ^ (row & 7);
    asrc[r] = A  + (size_t)(m0 + row)*TD + kq*8;
    bsrc[r] = Bw + (size_t)(n0 + row)*TD + kq*8;
    ldst[r] = Sp*16;
  }
  // rk fragment base (slot = (wc&1)*16 + r15), k = t*64 + {0,32} + kg*8
  const u16* rkp = rkb + (size_t)((m0 >> 13)*TS + (wc&1)*16 + r15)*TD + kg*8;

  f32x4 acc[8][4];
  #pragma unroll
  for (int i=0;i<8;i++){
    #pragma unroll
    for (int j=0;j<4;j++){ f32x4 z = {0,0,0,0}; acc[i][j] = z; }
  }
  f32x4 pacc[8];
  if constexpr (SIG){
    #pragma unroll
    for (int i=0;i<8;i++){ f32x4 z = {0,0,0,0}; pacc[i] = z; }
  }

  auto stage = [&](int t){
    char* slot = sL + (size_t)(t&1)*65536;
    int k0 = t*64;
    #pragma unroll
    for (int r=0;r<4;r++) gll16(asrc[r] + k0, slot + ldst[r]);
    #pragma unroll
    for (int r=0;r<4;r++) gll16(bsrc[r] + k0, slot + 32768 + ldst[r]);
  };

  auto compute = [&](int t, bf16x8 rk0, bf16x8 rk1){
    const char* sa = sL + (size_t)(t&1)*65536;
    const char* sb = sa + 32768;
    bf16x8 bfg[4], af[4];
    #pragma unroll
    for (int j=0;j<4;j++) bfg[j] = *(const bf16x8*)(sb + brd[j]);
    #pragma unroll
    for (int i=0;i<4;i++) af[i] = *(const bf16x8*)(sa + ard[i]);
    LGKM0();
    __builtin_amdgcn_sched_barrier(0);
    __builtin_amdgcn_s_setprio(1);
    #pragma unroll
    for (int i=0;i<4;i++){
      #pragma unroll
      for (int j=0;j<4;j++)
        acc[i][j] = __builtin_amdgcn_mfma_f32_16x16x32_bf16(af[i], bfg[j], acc[i][j], 0,0,0);
    }
    if constexpr (SIG){
      if (wcP){
        #pragma unroll
        for (int i=0;i<4;i++) pacc[i] = __builtin_amdgcn_mfma_f32_16x16x32_bf16(af[i], rk0, pacc[i], 0,0,0);
      }
    }
    __builtin_amdgcn_s_setprio(0);
    bf16x8 af2[4];
    #pragma unroll
    for (int i=0;i<4;i++) af2[i] = *(const bf16x8*)(sa + (ard[4+i]));
    LGKM0();
    __builtin_amdgcn_sched_barrier(0);
    __builtin_amdgcn_s_setprio(1);
    #pragma unroll
    for (int i=0;i<4;i++){
      #pragma unroll
      for (int j=0;j<4;j++)
        acc[4+i][j] = __builtin_amdgcn_mfma_f32_16x16x32_bf16(af2[i], bfg[j], acc[4+i][j], 0,0,0);
    }
    if constexpr (SIG){
      if (wcP){
        #pragma unroll
        for (int i=0;i<4;i++) pacc[4+i] = __builtin_amdgcn_mfma_f32_16x16x32_bf16(af2[i], rk0, pacc[4+i], 0,0,0);
      }
    }
    __builtin_amdgcn_s_setprio(0);
    bf16x8 bfh[4], ag[4];
    #pragma unroll
    for (int j=0;j<4;j++) bfh[j] = *(const bf16x8*)(sb + (brd[j]^64));
    #pragma unroll
    for (int i=0;i<4;i++) ag[i] = *(const bf16x8*)(sa + (ard[i]^64));
    LGKM0();
    __builtin_amdgcn_sched_barrier(0);
    __builtin_amdgcn_s_setprio(1);
    #pragma unroll
    for (int i=0;i<4;i++){
      #pragma unroll
      for (int j=0;j<4;j++)
        acc[i][j] = __builtin_amdgcn_mfma_f32_16x16x32_bf16(ag[i], bfh[j], acc[i][j], 0,0,0);
    }
    if constexpr (SIG){
      if (wcP){
        #pragma unroll
        for (int i=0;i<4;i++) pacc[i] = __builtin_amdgcn_mfma_f32_16x16x32_bf16(ag[i], rk1, pacc[i], 0,0,0);
      }
    }
    __builtin_amdgcn_s_setprio(0);
    bf16x8 ag2[4];
    #pragma unroll
    for (int i=0;i<4;i++) ag2[i] = *(const bf16x8*)(sa + (ard[4+i]^64));
    LGKM0();
    __builtin_amdgcn_sched_barrier(0);
    __builtin_amdgcn_s_setprio(1);
    #pragma unroll
    for (int i=0;i<4;i++){
      #pragma unroll
      for (int j=0;j<4;j++)
        acc[4+i][j] = __builtin_amdgcn_mfma_f32_16x16x32_bf16(ag2[i], bfh[j], acc[4+i][j], 0,0,0);
    }
    if constexpr (SIG){
      if (wcP){
        #pragma unroll
        for (int i=0;i<4;i++) pacc[4+i] = __builtin_amdgcn_mfma_f32_16x16x32_bf16(ag2[i], rk1, pacc[4+i], 0,0,0);
      }
    }
    __builtin_amdgcn_s_setprio(0);
  };

  stage(0);
  for (int t=0; t<16; ++t){
    if (t > 0) __builtin_amdgcn_s_barrier();
    bf16x8 rk0, rk1;
    if (wcP){
      rk0 = *(const bf16x8*)(rkp + t*64);        // issued BEFORE stage(t+1):
      rk1 = *(const bf16x8*)(rkp + t*64 + 32);   // VMWAIT(8) covers them in-order
      __builtin_amdgcn_sched_barrier(0);
    }
    if (t < 15){
      stage(t+1);
      VMWAIT(8);
    } else {
      VMWAIT(0);
    }
    __builtin_amdgcn_sched_barrier(0);
    __builtin_amdgcn_s_barrier();
    compute(t, rk0, rk1);
  }

  if constexpr (SIG){
    // ---- in-kernel masked softmax over LDS ----
    float* Pf = (float*)sL;                 // [256][33] f32 (33.8KB)
    u16* Pb16 = (u16*)(sL + 33792);         // [256][40] u16 (20KB)
    __syncthreads();                        // all K-loop LDS reads retired
    if (wcP){
      #pragma unroll
      for (int i=0;i<8;i++){
        int tok = wr*128 + i*16 + kg*4;
        #pragma unroll
        for (int q=0;q<4;q++)
          Pf[(tok+q)*33 + (wc&1)*16 + r15] = pacc[i][q];
      }
    }
    __syncthreads();
    if (tid < 256){
      float v[32];
      float mx = -1e30f;
      #pragma unroll
      for (int s=0;s<32;s++){
        float t = Pf[tid*33 + s];
        v[s] = t;
        if (s >= smin) mx = fmaxf(mx, t);
      }
      float sum = 0.f;
      #pragma unroll
      for (int s=0;s<32;s++){
        float e = (s >= smin) ? __expf(v[s]-mx) : 0.f;
        v[s] = e; sum += e;
      }
      float rs = 1.f/sum;
      #pragma unroll
      for (int s=0;s<32;s++) Pb16[tid*40 + s] = f2b(v[s]*rs);
    }
    __syncthreads();

    // ---- PV + gate + residual epilogue (P from LDS) ----
    int b = m0 >> 13;
    bf16x8 vfrag[4];
    #pragma unroll
    for (int j=0;j<4;j++){
      int n = n0 + wc*64 + j*16 + r15;
      vfrag[j] = *(const bf16x8*)(rvT + ((size_t)b*TD + n)*TS + kg*8);
    }
    #pragma unroll
    for (int i=0;i<8;i++){
      bf16x8 pfrag = *(const bf16x8*)(Pb16 + (wr*128 + i*16 + r15)*40 + kg*8);
      f32x4 rd[4];
      #pragma unroll
      for (int j=0;j<4;j++){
        f32x4 z = {0,0,0,0};
        rd[j] = __builtin_amdgcn_mfma_f32_16x16x32_bf16(pfrag, vfrag[j], z, 0,0,0);
      }
      int mrow = m0 + wr*128 + i*16 + kg*4;
      #pragma unroll
      for (int j=0;j<4;j++){
        int n = n0 + wc*64 + j*16 + r15;
        float bj = bias[n];
        #pragma unroll
        for (int q=0;q<4;q++){
          float g = 1.f/(1.f + __expf(-(acc[i][j][q] + bj)));
          size_t idx = (size_t)(mrow + q)*TD + n;
          float xv = b2f(A[idx]);   // A == xb
          ((u16*)Cp)[idx] = f2b(xv + g*rd[j][q]);
        }
      }
    }
  } else {
    #pragma unroll
    for (int i=0;i<8;i++){
      int mrow = m0 + wr*128 + i*16 + kg*4;
      #pragma unroll
      for (int j=0;j<4;j++){
        int n = n0 + wc*64 + j*16 + r15;
        #pragma unroll
        for (int q=0;q<4;q++){
          size_t idx = (size_t)(mrow + q)*TD + n;
          ((float*)Cp)[idx] = acc[i][j][q];
        }
      }
    }
  }
}

extern "C" void kernel_launch(void* const* d_in, const int* in_sizes, int n_in,
                              void* d_out, int out_size, void* d_ws, size_t ws_size,
                              hipStream_t stream){
  const float* x   = (const float*)d_in[0];
  const float* gw  = (const float*)d_in[1];
  const float* gb  = (const float*)d_in[2];
  const float* rqw = (const float*)d_in[3];
  const float* rkw = (const float*)d_in[4];
  const float* rvw = (const float*)d_in[5];
  const float* ow  = (const float*)d_in[6];
  const float* ms  = (const float*)d_in[7];
  const float* wqw = (const float*)d_in[8];
  const float* wkw = (const float*)d_in[9];
  const float* wvw = (const float*)d_in[10];
  float* out = (float*)d_out;
  float* mem_out = out + (size_t)BT*TD;   // byte offset 134217728

  // d_out scratch (dead before final GEMM overwrites [0,128MB)):
  char* o = (char*)d_out;
  u16* xb    = (u16*)o;                  // 64MB
  u16* gwb   = (u16*)(o + 69206016);     // 2MB
  u16* wvwb  = (u16*)(o + 71303168);     // 2MB
  u16* rkwb  = (u16*)(o + 73400320);     // 2MB
  u16* rvwb  = (u16*)(o + 75497472);     // 2MB
  u16* xbarb = (u16*)(o + 79757312);     // 256KB
  u16* rvT   = (u16*)(o + 80281600);     // 256KB
  u16* WvT   = (u16*)(o + 84934656);     // 2MB
  u16* WrqT  = (u16*)(o + 87031808);     // 2MB
  u16* WqT   = (u16*)(o + 89128960);     // 2MB
  u16* WkT   = (u16*)(o + 91226112);     // 2MB
  u16* We    = (u16*)(o + 95420416);     // 2MB
  u16* WdT   = (u16*)(o + 97517568);     // 2MB
  u16* WzT   = (u16*)(o + 99614720);     // 2MB
  u16* msb   = (u16*)(o + 101711872);    // 64KB
  u16* WrkT  = (u16*)(o + 103809024);    // 2MB
  u16* WgT   = (u16*)(o + 105906176);    // 2MB

  char* w = (char*)d_ws;
  u16*   gy    = (u16*)(w);                    // 64MB (y = x + g*read)
  float* wqkb  = (float*)(w + 67108864);       // 128KB
  float* qkp   = (float*)(w + 67239936);       // 256KB (qk partials [2][32][1024])
  u16*   rkb   = (u16*)(w + 67502080);         // 256KB
  u16*   owb   = (u16*)(w + 68288512);         // 2MB

  // 1. transposes: WvT,WrqT,WqT,WkT,WrkT ; ms->bf16
  k_tran<<<dim3(16,16,6),256,0,stream>>>(wvw, rqw, wqw, wkw, rkw, ms,
                                         WvT, WrqT, WqT, WkT, WrkT, msb);
  // 2. WzT = (Wq^T@Wk)^T ; WgT = (scale*Wrk^T@Wrq)^T
  k_smmw<<<dim3(8,8,2),512,0,stream>>>(WqT, WkT, WzT, 1, 1.f,
                                       WrkT, WrqT, WgT, 1, 1.f/32.f);
  // 3. qk partials = ms @ Wz (K-split 2)
  k_qk32<<<dim3(8,2),512,0,stream>>>(msb, WzT, qkp);
  // 4. xb = bf16(x); wqk = x . qk[seg]; + convert 5 weight matrices
  k_convdot<<<7168,256,0,stream>>>(x, qkp, xb, wqkb,
                                   gw, ow, wvw, rkw, rvw,
                                   gwb, owb, wvwb, rkwb, rvwb);
  // 5. merged: xbar = softmax(wqk).x  +  {We = Wrv@Wv ; WdT = (Wv^T@Wg)^T}
  k_wattn_smm<<<384,512,0,stream>>>(wqkb, xb, xbarb,
                                    rvwb, WvT, We,
                                    WvT, WgT, WdT);
  // 6. mem_out = xbar@Wv^T (f32); rk~ = xbar@Wd (bf16); rvT = (xbar@We^T)^T
  k_xbar3<<<dim3(8,1,3),512,0,stream>>>(xbarb, wvwb, WdT, We, mem_out, rkb, rvT);
  // 7. y = x + sigmoid(x@gate_w^T + gb) * (softmax(mask(xb@rk~^T)) @ rvT)  [fully fused]
  k_gemm<true><<<512,512,0,stream>>>(xb, gwb, gb, gy, rkb, rvT);
  // 8. out = y @ output_w^T
  k_gemm<false><<<512,512,0,stream>>>(gy, owb, nullptr, d_out, nullptr, nullptr);
}